// Round 1
// 787.797 us; speedup vs baseline: 1.5310x; 1.5310x over previous
//
#include <hip/hip_runtime.h>
#include <hip/hip_bf16.h>

// CRF forward + gold score via MFMA.
// B=4096, L=1024, T=32. One wave per 16 sequences; lane = (batch n=lane&15, q=lane>>4).
// Per step: acc[b,s] = sum_prev Mexp[s][prev] * E[prev,b] via 2x mfma_f32_16x16x32_bf16
// with ROW-PERMUTED A so that the D layout (lane holds states 8q..8q+7 for batch n)
// is exactly the B-fragment layout of the next step -> no cross-lane E movement.
//
// Normalization (per step, keeps E[b,0] == 1):
//   E_new[s] = c[s] * exp(f[s] - delta), delta = log(c[0]) + f00
//            = (c[s] * exp(f[s] - f00)) * rcp(c[0])
// so the serial chain is mfma -> bpermute(c[0]) -> rcp -> mul -> cvt; the exp()s
// use 8-step-old prefetched data and the log() (for mAcc) is off the chain.
//
// Prefetch ring is STATICALLY indexed (outer x127 loop, inner fully-unrolled x8)
// so it lives in VGPRs. Previous version indexed it with (l&7) under unroll-4,
// which demoted the ring to scratch (VGPR_Count=76 proved it) and cost ~1400
// cycles/step in scratch round-trips.

#define BATCH 4096
#define LSEQ  1024
#define T     32
#define START 30
#define STOP  31

typedef __attribute__((ext_vector_type(8))) short short8;
typedef __attribute__((ext_vector_type(4))) float f32x4;

static __device__ __forceinline__ short bf16b(float x) {
    union { __hip_bfloat16 h; short s; } u;
    u.h = __float2bfloat16(x);
    return u.s;
}

__global__ __launch_bounds__(64) void crf_fwd_mfma(
    const float* __restrict__ feats,   // [B, L, T]
    const float* __restrict__ trans,   // [T, T] (next, prev)
    const int*   __restrict__ tags,    // [B, L]
    float*       __restrict__ out)     // [B]
{
    __shared__ float trans_s[T * T];
    const int lane = threadIdx.x;      // 0..63
    for (int i = lane; i < T * T; i += 64) trans_s[i] = trans[i];
    __syncthreads();

    const int n = lane & 15;           // batch within the wave's group of 16
    const int q = lane >> 4;           // quadrant: owns states 8q..8q+7
    const int b = blockIdx.x * 16 + n;

    // A fragments (Mexp, row-permuted). A[m][k]: m = lane&15, k = 8q + j.
    // A1 row m -> state 8*(m>>2)+(m&3); A2 row m -> that +4. exp(-10000)==0 exact.
    short8 a1, a2;
    {
        const int s1 = 8 * (n >> 2) + (n & 3);
        const int s2 = s1 + 4;
#pragma unroll
        for (int j = 0; j < 8; ++j) {
            a1[j] = bf16b(__expf(trans_s[s1 * T + 8 * q + j]));
            a2[j] = bf16b(__expf(trans_s[s2 * T + 8 * q + j]));
        }
    }

    // B fragment: E[k = 8q+j][n]. Init fv: START=0, rest -1e4 -> E = one-hot(START).
    short8 bfrag;
#pragma unroll
    for (int j = 0; j < 8; ++j) bfrag[j] = 0;
    if (q == 3) bfrag[6] = bf16b(1.0f);          // state 30 = 8*3+6

    const f32x4* fp = (const f32x4*)(feats + (size_t)b * (LSEQ * T) + 8 * q);
    const int*   tb = tags + (size_t)b * LSEQ;

    // 8-deep register ring: 2 float4 (states 8q..8q+7) + tag per step.
    // All indices below are compile-time constants -> stays in VGPRs.
    f32x4 fr0[8], fr1[8];
    int   tbuf[8];
#pragma unroll
    for (int i = 0; i < 8; ++i) {
        fr0[i] = fp[i * 8];
        fr1[i] = fp[i * 8 + 1];
        tbuf[i] = tb[i];
    }

    float mAcc  = 0.0f;       // sum_l log(c[0]_l)        (uniform across q)
    float mAccF = 0.0f;       // sum_l f00_l              (uniform across q)
    float gold_trans = 0.0f;  // uniform across q
    float gold_emit  = 0.0f;  // per-lane partial, reduced at end
    int   prev_tag = START;
    float ev[8];              // fp32 E of the current step (kept for epilogue)

    const f32x4 zacc = {0.f, 0.f, 0.f, 0.f};

#define CRF_STEP(l, slot, DO_PF)                                               \
    {                                                                          \
        const f32x4 f0  = fr0[slot];                                           \
        const f32x4 f1  = fr1[slot];                                           \
        const int   tag = tbuf[slot];                                          \
        if (DO_PF) {                                                           \
            fr0[slot]  = fp[((l) + 8) * 8];                                    \
            fr1[slot]  = fp[((l) + 8) * 8 + 1];                                \
            tbuf[slot] = tb[(l) + 8];                                          \
        }                                                                      \
        /* off-chain: f00 broadcast + exp() on 8-step-old data */              \
        const float f00 = __shfl(f0[0], n, 64);                                \
        float e0[4], e1[4];                                                    \
        _Pragma("unroll")                                                      \
        for (int r = 0; r < 4; ++r) {                                          \
            e0[r] = __expf(f0[r] - f00);                                       \
            e1[r] = __expf(f1[r] - f00);                                       \
        }                                                                      \
        f32x4 c1 = __builtin_amdgcn_mfma_f32_16x16x32_bf16(a1, bfrag, zacc, 0, 0, 0); \
        f32x4 c2 = __builtin_amdgcn_mfma_f32_16x16x32_bf16(a2, bfrag, zacc, 0, 0, 0); \
        /* chain: mfma -> bpermute -> rcp -> mul -> cvt */                     \
        const float cb  = __shfl(c1[0], n, 64);  /* c[0], valid in q==0 lane */ \
        const float inv = __builtin_amdgcn_rcpf(cb);                           \
        mAcc  += __logf(cb);  /* off-chain, only needed at the end */          \
        mAccF += f00;                                                          \
        _Pragma("unroll")                                                      \
        for (int r = 0; r < 4; ++r) {                                          \
            ev[r]     = (c1[r] * e0[r]) * inv;                                 \
            ev[4 + r] = (c2[r] * e1[r]) * inv;                                 \
        }                                                                      \
        _Pragma("unroll")                                                      \
        for (int j = 0; j < 8; ++j) bfrag[j] = bf16b(ev[j]);                   \
        /* gold: transitions (uniform) + emission (owned by lane q==tag>>3) */ \
        gold_trans += trans_s[tag * T + prev_tag];                             \
        {                                                                      \
            const f32x4 fs  = (tag & 4) ? f1 : f0;                             \
            const float p01 = (tag & 1) ? fs[1] : fs[0];                       \
            const float p23 = (tag & 1) ? fs[3] : fs[2];                       \
            const float pk  = (tag & 2) ? p23 : p01;                           \
            if ((tag >> 3) == q) gold_emit += pk;                              \
        }                                                                      \
        prev_tag = tag;                                                        \
    }

    // main loop: outer x127, inner fully unrolled x8 so slot == i is constant
    for (int lo = 0; lo < LSEQ - 8; lo += 8) {
#pragma unroll
        for (int i = 0; i < 8; ++i) CRF_STEP(lo + i, i, 1)
    }
    // epilogue: last 8 steps, no prefetch (slot = i since 1016 % 8 == 0)
#pragma unroll
    for (int i = 0; i < 8; ++i) CRF_STEP(LSEQ - 8 + i, i, 0)
#undef CRF_STEP

    // alpha = (mAcc + mAccF) + log(sum_s E[s] * Mexp[STOP][s])
    float s = 0.0f;
#pragma unroll
    for (int j = 0; j < 8; ++j)
        s += ev[j] * __expf(trans_s[STOP * T + 8 * q + j]);
    s += __shfl_xor(s, 16, 64);
    s += __shfl_xor(s, 32, 64);
    const float alpha = mAcc + mAccF + __logf(s);

    float ge = gold_emit;
    ge += __shfl_xor(ge, 16, 64);
    ge += __shfl_xor(ge, 32, 64);
    const float gold = ge + gold_trans + trans_s[STOP * T + prev_tag];

    if (lane < 16) out[b] = alpha - gold;
}

extern "C" void kernel_launch(void* const* d_in, const int* in_sizes, int n_in,
                              void* d_out, int out_size, void* d_ws, size_t ws_size,
                              hipStream_t stream) {
    const float* feats = (const float*)d_in[0];
    const float* trans = (const float*)d_in[1];
    const int*   tags  = (const int*)d_in[2];
    float*       out   = (float*)d_out;

    // 16 sequences per 64-thread block -> 256 blocks = 1 wave per CU
    crf_fwd_mfma<<<BATCH / 16, 64, 0, stream>>>(feats, trans, tags, out);
}